// Round 1
// baseline (271.778 us; speedup 1.0000x reference)
//
#include <hip/hip_runtime.h>
#include <cstdint>
#include <cstddef>

#define BB 128
#define NN 512
#define EE 512
#define KK 256

__device__ __forceinline__ float wave_reduce_max(float v) {
#pragma unroll
  for (int off = 32; off >= 1; off >>= 1) v = fmaxf(v, __shfl_xor(v, off, 64));
  return v;
}
__device__ __forceinline__ float wave_reduce_sum(float v) {
#pragma unroll
  for (int off = 32; off >= 1; off >>= 1) v += __shfl_xor(v, off, 64);
  return v;
}

// Lower median (0-based rank 127) of 256 nonnegative values held 4 per lane
// across the 64 lanes of a wave. Exact: early-exit when exactly 128 values
// lie strictly below the pivot (their max is rank 127); otherwise bisection
// converges lo,hi to adjacent floats bracketing the answer (handles ties).
__device__ __forceinline__ float wave_median256(float a0, float a1, float a2, float a3) {
  float m = fmaxf(fmaxf(a0, a1), fmaxf(a2, a3));
  m = wave_reduce_max(m);
  float hi = __uint_as_float(__float_as_uint(m) + 1u);  // cnt(hi) == 256 >= 128
  float lo = 0.f;
  float pivot = hi;
  bool found = false;
  for (int it = 0; it < 40; ++it) {
    pivot = 0.5f * (lo + hi);
    int cnt = __popcll(__ballot(a0 < pivot)) + __popcll(__ballot(a1 < pivot)) +
              __popcll(__ballot(a2 < pivot)) + __popcll(__ballot(a3 < pivot));
    if (cnt == 128) { found = true; break; }
    if (cnt < 128) lo = pivot; else hi = pivot;
  }
  float p = found ? pivot : hi;
  float s0 = (a0 < p) ? a0 : 0.f;
  float s1 = (a1 < p) ? a1 : 0.f;
  float s2 = (a2 < p) ? a2 : 0.f;
  float s3 = (a3 < p) ? a3 : 0.f;
  return wave_reduce_max(fmaxf(fmaxf(s0, s1), fmaxf(s2, s3)));
}

__global__ void kmax(const float* __restrict__ head, float* __restrict__ ws_max) {
  int b = blockIdx.x;
  int lane = threadIdx.x;  // blockDim = 64
  const float* h = head + (size_t)b * NN;
  float m = -INFINITY;
#pragma unroll
  for (int i = 0; i < NN / 64; ++i) m = fmaxf(m, h[lane + 64 * i]);
  m = wave_reduce_max(m);
  if (lane == 0) ws_max[b] = m;
}

// Stage 1: per (b,n) l1 = sum of two chunk-medians of |errs|, then exp
// relaxation scalars lam/mu/delta + headterm. 32 columns per block.
__global__ __launch_bounds__(256) void kstage1(
    const float* __restrict__ head, const float* __restrict__ errs,
    const float* __restrict__ ws_max, float* __restrict__ ws_lam,
    float* __restrict__ ws_delta, float* __restrict__ ws_ht) {
  // stride 34 floats: 8B-aligned rows (float2 writes) and 4-way-conflict
  // column reads (bank = (2*lane + j) % 32). 34816 B of LDS.
  __shared__ float tile[256 * 34];
  __shared__ float l1buf[32];
  const int b = blockIdx.x >> 4;
  const int n0 = (blockIdx.x & 15) * 32;
  const int tid = threadIdx.x;
  const int wave = tid >> 6, lane = tid & 63;
  if (tid < 32) l1buf[tid] = 0.f;
  __syncthreads();
  const int tr = tid >> 3, tc = (tid & 7) * 4;
  for (int c = 0; c < 2; ++c) {
    const float* src = errs + ((size_t)(b * EE + c * 256)) * NN + n0;
#pragma unroll
    for (int i = 0; i < 8; ++i) {
      int row = i * 32 + tr;
      float4 v = *(const float4*)(src + (size_t)row * NN + tc);
      float* dst = &tile[row * 34 + tc];
      *(float2*)dst = make_float2(v.x, v.y);
      *(float2*)(dst + 2) = make_float2(v.z, v.w);
    }
    __syncthreads();
#pragma unroll 1
    for (int jj = 0; jj < 8; ++jj) {
      int j = wave * 8 + jj;
      float a0 = fabsf(tile[lane * 34 + j]);
      float a1 = fabsf(tile[(lane + 64) * 34 + j]);
      float a2 = fabsf(tile[(lane + 128) * 34 + j]);
      float a3 = fabsf(tile[(lane + 192) * 34 + j]);
      float med = wave_median256(a0, a1, a2, a3);
      if (lane == 0) l1buf[j] += med;
    }
    __syncthreads();
  }
  if (tid < 32) {
    int n = n0 + tid;
    float l1 = l1buf[tid];
    float th = head[(size_t)b * NN + n] - ws_max[b];
    float lb = th - l1, ub = th + l1;
    float lam, mu;
    float delta;
    if (ub == lb) {  // is_tight (match reference's rounded comparison)
      lam = 0.f; mu = expf(ub); delta = 0.f;
    } else {
      float elb = expf(lb), eub = expf(ub);
      float lam_s = (eub - elb) / (ub - lb + 1e-6f);
      lam = fminf(lam_s, expf(lb + 0.9f));
      float ub0 = (lam > lam_s) ? (elb - lam * lb) : (eub - lam * ub);
      float t = lam * (1.f - logf(lam));
      mu = 0.5f * (t + ub0);
      delta = 0.5f * (ub0 - t);
    }
    size_t o = (size_t)b * NN + n;
    ws_lam[o] = lam;
    ws_delta[o] = delta;
    ws_ht[o] = th * lam + mu;
  }
}

// Stage 2: exp_errs[b, 0:512] = errs[b,e,:] . lam[b,:]
//          exp_errs[b, 512:768] = cauchy_exp[b,j,:] . delta[b,:]
// wave-per-row, fully coalesced float4 streaming.
__global__ __launch_bounds__(256) void kstage2(
    const float* __restrict__ errs, const float* __restrict__ cexp,
    const float* __restrict__ ws_lam, const float* __restrict__ ws_delta,
    float* __restrict__ ws_ee) {
  const int blk = blockIdx.x;
  const int b = blk / 12, part = blk % 12;
  const int wave = threadIdx.x >> 6, lane = threadIdx.x & 63;
  const bool is_err = part < 8;
  const float* wsrc = (is_err ? ws_lam : ws_delta) + (size_t)b * NN;
  float4 wa = *(const float4*)(wsrc + 4 * lane);
  float4 wb = *(const float4*)(wsrc + 256 + 4 * lane);
  const int r0 = (is_err ? part : part - 8) * 64 + wave * 16;
  const float* base = is_err ? (errs + (size_t)b * EE * NN) : (cexp + (size_t)b * KK * NN);
  float* out = ws_ee + (size_t)b * 768 + (is_err ? 0 : EE);
#pragma unroll 1
  for (int i = 0; i < 16; ++i) {
    int r = r0 + i;
    const float* rp = base + (size_t)r * NN;
    float4 x = *(const float4*)(rp + 4 * lane);
    float4 y = *(const float4*)(rp + 256 + 4 * lane);
    float s = x.x * wa.x + x.y * wa.y + x.z * wa.z + x.w * wa.w +
              y.x * wb.x + y.y * wb.y + y.z * wb.z + y.w * wb.w;
    s = wave_reduce_sum(s);
    if (lane == 0) out[r] = s;
  }
}

// Stage 3: per b: exp_head sum, 3 medians of 256 over exp_errs, log
// relaxation, write outputs.
__global__ __launch_bounds__(256) void kstage3(
    const float* __restrict__ clog, const float* __restrict__ ws_max,
    const float* __restrict__ ws_ht, const float* __restrict__ ws_ee,
    float* __restrict__ out) {
  __shared__ float red[4];
  __shared__ float meds[3];
  __shared__ float sc[2];
  const int b = blockIdx.x;
  const int tid = threadIdx.x, wave = tid >> 6, lane = tid & 63;
  float s = ws_ht[(size_t)b * NN + tid] + ws_ht[(size_t)b * NN + 256 + tid];
  s = wave_reduce_sum(s);
  if (lane == 0) red[wave] = s;
  const float* eb = ws_ee + (size_t)b * 768;
  if (wave < 3) {
    const float* p = eb + wave * 256;
    float a0 = fabsf(p[lane]), a1 = fabsf(p[lane + 64]);
    float a2 = fabsf(p[lane + 128]), a3 = fabsf(p[lane + 192]);
    float med = wave_median256(a0, a1, a2, a3);
    if (lane == 0) meds[wave] = med;
  }
  __syncthreads();
  if (tid == 0) {
    float eh = red[0] + red[1] + red[2] + red[3];
    float l1 = meds[0] + meds[1] + meds[2];
    float lb = eh - l1, ub = eh + l1;
    float lam, mu, delta;
    if (ub == lb) {
      lam = 0.f; mu = logf(ub); delta = 0.f;
    } else {
      float llb = logf(lb + 1e-6f);
      float lam_s = (logf(ub) - llb) / (ub - lb + 1e-6f);
      lam = lam_s;
      float lb0 = llb - lb * lam;  // reference's where(lam<lam_s,...) always takes else
      float t = -logf(lam) - 1.f;
      mu = 0.5f * (t + lb0);
      delta = 0.5f * (t - lb0);
    }
    sc[0] = lam; sc[1] = delta;
    out[b] = eh * lam + mu + ws_max[b];
  }
  __syncthreads();
  float lam = sc[0], delta = sc[1];
  float* ob = out + BB + (size_t)b * 1024;
  ob[tid] = eb[tid] * lam;
  ob[tid + 256] = eb[tid + 256] * lam;
  ob[tid + 512] = eb[tid + 512] * lam;
  ob[tid + 768] = delta * clog[(size_t)b * KK + tid];
}

extern "C" void kernel_launch(void* const* d_in, const int* in_sizes, int n_in,
                              void* d_out, int out_size, void* d_ws, size_t ws_size,
                              hipStream_t stream) {
  const float* head = (const float*)d_in[0];   // (128, 512)
  const float* errs = (const float*)d_in[1];   // (65536, 512)
  const float* cexp = (const float*)d_in[2];   // (128, 256, 512)
  const float* clog = (const float*)d_in[3];   // (128, 256)
  float* out = (float*)d_out;                  // 128 + 131072 floats

  float* ws = (float*)d_ws;
  float* ws_max = ws;                       // 128
  float* ws_lam = ws + 128;                 // 65536
  float* ws_delta = ws_lam + BB * NN;       // 65536
  float* ws_ht = ws_delta + BB * NN;        // 65536
  float* ws_ee = ws_ht + BB * NN;           // 128*768 = 98304

  hipLaunchKernelGGL(kmax, dim3(BB), dim3(64), 0, stream, head, ws_max);
  hipLaunchKernelGGL(kstage1, dim3(BB * 16), dim3(256), 0, stream,
                     head, errs, ws_max, ws_lam, ws_delta, ws_ht);
  hipLaunchKernelGGL(kstage2, dim3(BB * 12), dim3(256), 0, stream,
                     errs, cexp, ws_lam, ws_delta, ws_ee);
  hipLaunchKernelGGL(kstage3, dim3(BB), dim3(256), 0, stream,
                     clog, ws_max, ws_ht, ws_ee, out);
}